// Round 8
// baseline (141.622 us; speedup 1.0000x reference)
//
#include <hip/hip_runtime.h>
#include <hip/hip_bf16.h>

// ---- problem constants ----
#define B_IMG   128
#define CH      3
#define HW      224
#define NPATCH  196          // tokens per image
#define TOKENS  25088        // B_IMG * NPATCH
#define FDIM    768          // C*P*P (K of the GEMM)
#define DDIM    768          // output embed dim (N of the GEMM)
#define OUT_TOKENS ((size_t)TOKENS * DDIM)     // positions follow in d_out

#define WCONV_BLOCKS 576     // 768*768/4/256
#define POS_BLOCKS   98      // 25088/256

typedef short short8 __attribute__((ext_vector_type(8)));
typedef float f32x4  __attribute__((ext_vector_type(4)));

static __device__ __forceinline__ unsigned short f2bf(float v) {
  unsigned u = __float_as_uint(v);
  unsigned r = u + 0x7fffu + ((u >> 16) & 1u);
  return (unsigned short)(r >> 16);
}

static __device__ __forceinline__ void gload16(const short* g, short* l) {
  __builtin_amdgcn_global_load_lds(
      (const __attribute__((address_space(1))) void*)g,
      (__attribute__((address_space(3))) void*)l,
      16, 0, 0);
}

// ---- kernel 1: W -> bf16, and positions ----
__global__ __launch_bounds__(256) void prep2_kernel(
    const float* __restrict__ W, const int* __restrict__ ys,
    const int* __restrict__ xs, short* __restrict__ Wbf,
    float* __restrict__ pos) {
  const int blk = blockIdx.x;
  if (blk < WCONV_BLOCKS) {
    int i = (blk * 256 + threadIdx.x) * 4;
    float4 v = *(const float4*)&W[i];
    ushort4 o;
    o.x = f2bf(v.x); o.y = f2bf(v.y); o.z = f2bf(v.z); o.w = f2bf(v.w);
    *(ushort4*)&Wbf[i] = o;
  } else {
    int t = (blk - WCONV_BLOCKS) * 256 + threadIdx.x;   // 0..25087 exact
    pos[2 * t]     = (float)ys[t];
    pos[2 * t + 1] = (float)xs[t];
  }
}

// ---- kernel 2: FUSED gather + 128x128 bf16 MFMA GEMM ----
// A is gathered from x on the fly: K-step kt of token row = patch rows
// (py0, py0+1) of channel c (c=kt>>3, py0=(kt&7)*2) — two contiguous
// 16-float segments of x. Per lane: fixed 8 (row,seg) base offsets
// (computed once), per step only scalar koff = c*50176 + py0*224 changes.
// f32 loads -> f2bf pack -> ds_write_b32 into As[128][32] (same layout the
// R1 compute consumes). B staged via global_load_lds as before.
// Schedule: R1-style drain (proven correct & best-equal): issue A(s+1) regs
// + B(s+1) gloads, compute tile s (MFMA shadows latency), vmcnt(0),
// ds_write A(s+1), __syncthreads.
__global__ __launch_bounds__(256) void fused_kernel(
    const float* __restrict__ x, const int* __restrict__ ys,
    const int* __restrict__ xs, const short* __restrict__ Bw,
    const float* __restrict__ bias, float* __restrict__ C) {
  __shared__ short As[2][128 * 32];
  __shared__ short Bs[2][128 * 32];

  const int tid  = threadIdx.x;
  const int w    = tid >> 6;
  const int l    = tid & 63;
  const int wrow = w >> 1;
  const int wcol = w & 1;
  const int lr   = l & 15;
  const int lg   = l >> 4;

  // bijective XCD swizzle: 1176 = 8*147 (R2 measured FETCH 118->34.6 MB)
  const int id  = blockIdx.x;
  const int nid = (id & 7) * 147 + (id >> 3);
  const int m0  = (nid / 6) * 128;
  const int n0  = (nid % 6) * 128;

  // ---- A-gather lane geometry (fixed per lane) ----
  // h = l>>3 (0..7): row_in_instr = h>>1, seg = h&1; px pair = (l&7)*2.
  // pass q (0..7): local row = w*32 + q*4 + (h>>1).
  const int h   = l >> 3;
  const int seg = h & 1;
  const int px0 = (l & 7) * 2;
  unsigned off8[8];
#pragma unroll
  for (int q = 0; q < 8; ++q) {
    const int row = w * 32 + q * 4 + (h >> 1);
    const int tok = m0 + row;
    const int b   = tok / NPATCH;              // compiler magic-div
    const int y   = ys[tok];
    const int xc  = xs[tok];
    // x index = b*150528 + c*50176 + (y+py0+seg)*224 + xc + px0
    off8[q] = (unsigned)(b * 150528 + (y + seg) * 224 + xc + px0);
  }
  // LDS u32-index for pass q: row*16 + seg*8 + (l&7)
  const int ldsb = (h >> 1) * 16 + seg * 8 + (l & 7);

  float bs[4];
#pragma unroll
  for (int ni = 0; ni < 4; ++ni) bs[ni] = bias[n0 + wcol * 64 + ni * 16 + lr];

  f32x4 acc[4][4];
  const f32x4 z = {0.f, 0.f, 0.f, 0.f};
#pragma unroll
  for (int mi = 0; mi < 4; ++mi)
#pragma unroll
    for (int ni = 0; ni < 4; ++ni) acc[mi][ni] = z;

  // B staging: wave stages 32 rows (2 gload16 of 16 rows each)
  const int rw = w * 32;
  const short* gB = Bw + (size_t)(n0 + rw + (l >> 2)) * FDIM + ((l & 3) << 3);
  const int lB = rw * 32;

  float av[16];   // in-flight A f32 for one K-step (8 passes x 2)

#define ISSUE_A(KT)                                                       \
  do {                                                                    \
    const int koff_ = ((KT) >> 3) * 50176 + (((KT) & 7) * 2) * 224;       \
    _Pragma("unroll")                                                     \
    for (int q = 0; q < 8; ++q) {                                         \
      av[2 * q]     = x[off8[q] + koff_];                                 \
      av[2 * q + 1] = x[off8[q] + koff_ + 1];                             \
    }                                                                     \
  } while (0)

#define STAGE_B(BUF, KT)                                                  \
  do {                                                                    \
    const int ko_ = (KT) * 32;                                            \
    gload16(gB + ko_, &Bs[(BUF)][lB]);                                    \
    gload16(gB + 16 * FDIM + ko_, &Bs[(BUF)][lB + 16 * 32]);              \
  } while (0)

#define WRITE_A(BUF)                                                      \
  do {                                                                    \
    unsigned* dst_ = (unsigned*)&As[(BUF)][0];                            \
    _Pragma("unroll")                                                     \
    for (int q = 0; q < 8; ++q) {                                         \
      unsigned pk_ = (unsigned)f2bf(av[2 * q]) |                          \
                     ((unsigned)f2bf(av[2 * q + 1]) << 16);               \
      dst_[w * 512 + q * 64 + ldsb] = pk_;                                \
    }                                                                     \
  } while (0)

#define COMPUTE(BUF)                                                      \
  do {                                                                    \
    const short* Ab_ = As[(BUF)];                                         \
    const short* Bb_ = Bs[(BUF)];                                         \
    short8 a_[4], b_[4];                                                  \
    const int koff_ = lg * 8;                                             \
    _Pragma("unroll")                                                     \
    for (int mi = 0; mi < 4; ++mi)                                        \
      a_[mi] = *(const short8*)&Ab_[(wrow * 64 + mi * 16 + lr) * 32 + koff_]; \
    _Pragma("unroll")                                                     \
    for (int ni = 0; ni < 4; ++ni)                                        \
      b_[ni] = *(const short8*)&Bb_[(wcol * 64 + ni * 16 + lr) * 32 + koff_]; \
    __builtin_amdgcn_s_setprio(1);                                        \
    _Pragma("unroll")                                                     \
    for (int mi = 0; mi < 4; ++mi)                                        \
      _Pragma("unroll")                                                   \
      for (int ni = 0; ni < 4; ++ni)                                      \
        acc[mi][ni] = __builtin_amdgcn_mfma_f32_16x16x32_bf16(            \
            a_[mi], b_[ni], acc[mi][ni], 0, 0, 0);                        \
    __builtin_amdgcn_s_setprio(0);                                        \
  } while (0)

  // prologue: tile 0
  ISSUE_A(0);
  STAGE_B(0, 0);
  asm volatile("s_waitcnt vmcnt(0)" ::: "memory");
  WRITE_A(0);
  __syncthreads();

#pragma unroll 1
  for (int s = 0; s < 23; ++s) {
    ISSUE_A(s + 1);
    STAGE_B((s + 1) & 1, s + 1);
    COMPUTE(s & 1);
    asm volatile("s_waitcnt vmcnt(0)" ::: "memory");  // av + B gloads landed
    WRITE_A((s + 1) & 1);
    __syncthreads();   // lgkm0 publishes ds_writes; barrier
  }
  COMPUTE(1);          // tile 23 (23&1)

  // epilogue: C/D layout col = lane&15, row = (lane>>4)*4 + j
#pragma unroll
  for (int ni = 0; ni < 4; ++ni) {
    const int col = n0 + wcol * 64 + ni * 16 + lr;
#pragma unroll
    for (int mi = 0; mi < 4; ++mi) {
      const int row = m0 + wrow * 64 + mi * 16 + lg * 4;
      const f32x4 v = acc[mi][ni];
#pragma unroll
      for (int j = 0; j < 4; ++j)
        C[(size_t)(row + j) * DDIM + col] = v[j] + bs[ni];
    }
  }
#undef ISSUE_A
#undef STAGE_B
#undef WRITE_A
#undef COMPUTE
}

// ---- fallback (ws too small): naive fused f32, correct but slow ----
__global__ __launch_bounds__(256) void naive_kernel(
    const float* __restrict__ x, const int* __restrict__ ys,
    const int* __restrict__ xs, const float* __restrict__ W,
    const float* __restrict__ bias, float* __restrict__ out) {
  __shared__ float prow[FDIM];
  const int tok = blockIdx.x;
  const int t   = threadIdx.x;
  const int b   = tok / NPATCH;
  const int y   = ys[tok];
  const int xc  = xs[tok];
  for (int i = t; i < FDIM; i += 256) {
    int c = i >> 8, rem = i & 255, py = rem >> 4, px = rem & 15;
    prow[i] = x[((size_t)(b * CH + c) * HW + y + py) * HW + xc + px];
  }
  __syncthreads();
  for (int dd = 0; dd < 3; ++dd) {
    const int d = t + dd * 256;
    float s = bias[d];
    const float4* wr = (const float4*)&W[(size_t)d * FDIM];
    const float4* pr = (const float4*)prow;
    for (int f4 = 0; f4 < FDIM / 4; ++f4) {
      float4 wv = wr[f4];
      float4 pv = pr[f4];
      s += wv.x * pv.x + wv.y * pv.y + wv.z * pv.z + wv.w * pv.w;
    }
    out[(size_t)tok * DDIM + d] = s;
  }
  if (t == 0) {
    float* pos = out + OUT_TOKENS;
    pos[(size_t)tok * 2]     = (float)y;
    pos[(size_t)tok * 2 + 1] = (float)xc;
  }
}

extern "C" void kernel_launch(void* const* d_in, const int* in_sizes, int n_in,
                              void* d_out, int out_size, void* d_ws, size_t ws_size,
                              hipStream_t stream) {
  const float* x    = (const float*)d_in[0];
  const int*   ys   = (const int*)d_in[1];
  const int*   xs   = (const int*)d_in[2];
  const float* W    = (const float*)d_in[3];
  const float* bias = (const float*)d_in[4];
  float* out = (float*)d_out;
  float* pos = out + OUT_TOKENS;

  const size_t w_bytes = (size_t)DDIM * FDIM * 2;   // 1,179,648
  if (ws_size >= w_bytes) {
    short* Wbf = (short*)d_ws;
    prep2_kernel<<<WCONV_BLOCKS + POS_BLOCKS, 256, 0, stream>>>(
        W, ys, xs, Wbf, pos);
    fused_kernel<<<(TOKENS / 128) * (DDIM / 128), 256, 0, stream>>>(
        x, ys, xs, Wbf, bias, out);
  } else {
    naive_kernel<<<TOKENS, 256, 0, stream>>>(x, ys, xs, W, bias, out);
  }
}

// Round 9
// 86.258 us; speedup vs baseline: 1.6419x; 1.6419x over previous
//
#include <hip/hip_runtime.h>
#include <hip/hip_bf16.h>

// ---- problem constants ----
#define B_IMG   128
#define CH      3
#define HW      224
#define NPATCH  196          // tokens per image
#define TOKENS  25088        // B_IMG * NPATCH
#define PATCH   16
#define FDIM    768          // C*P*P (K of the GEMM)
#define DDIM    768          // output embed dim (N of the GEMM)
#define TOKELEMS ((size_t)TOKENS * FDIM)
#define OUT_TOKENS ((size_t)TOKENS * DDIM)     // positions follow in d_out

#define GATHER_BLOCKS (TOKENS * (FDIM / 4) / 256)   // 18816
#define WCONV_BLOCKS  ((DDIM * FDIM / 4) / 256)     // 576

typedef short short8 __attribute__((ext_vector_type(8)));
typedef float f32x4  __attribute__((ext_vector_type(4)));

static __device__ __forceinline__ unsigned short f2bf(float v) {
  unsigned u = __float_as_uint(v);
  unsigned r = u + 0x7fffu + ((u >> 16) & 1u);
  return (unsigned short)(r >> 16);
}

static __device__ __forceinline__ void gload16(const short* g, short* l) {
  __builtin_amdgcn_global_load_lds(
      (const __attribute__((address_space(1))) void*)g,
      (__attribute__((address_space(3))) void*)l,
      16, 0, 0);
}

// ---- kernel 1: gather patches -> bf16 [TOKENS][768] + positions, W -> bf16 ----
__global__ __launch_bounds__(256) void prep_kernel(
    const float* __restrict__ x, const int* __restrict__ ys,
    const int* __restrict__ xs, const float* __restrict__ W,
    short* __restrict__ patches, short* __restrict__ Wbf,
    float* __restrict__ pos) {
  const int blk = blockIdx.x;
  if (blk < GATHER_BLOCKS) {
    int e   = blk * 256 + threadIdx.x;      // quad index
    int tok = e / 192;
    int q   = e - tok * 192;
    int f   = q * 4;
    int b   = tok / NPATCH;
    int y   = ys[tok];
    int xc  = xs[tok];
    int c   = f >> 8;
    int rem = f & 255;
    int py  = rem >> 4;
    int px  = rem & 15;
    const float* src = x + ((size_t)(b * CH + c) * HW + (y + py)) * HW + xc + px;
    ushort4 o;
    o.x = f2bf(src[0]); o.y = f2bf(src[1]); o.z = f2bf(src[2]); o.w = f2bf(src[3]);
    *(ushort4*)&patches[(size_t)tok * FDIM + f] = o;
    if (q == 0) {
      pos[(size_t)tok * 2]     = (float)y;
      pos[(size_t)tok * 2 + 1] = (float)xc;
    }
  } else {
    int i = ((blk - GATHER_BLOCKS) * 256 + threadIdx.x) * 4;
    float4 v = *(const float4*)&W[i];
    ushort4 o;
    o.x = f2bf(v.x); o.y = f2bf(v.y); o.z = f2bf(v.z); o.w = f2bf(v.w);
    *(ushort4*)&Wbf[i] = o;
  }
}

// ---- kernel 2: 128x128 tile, BK=64 (12 steps), dbuf, XOR-swizzled LDS ----
// Axis under test vs R1/R2/R3/R5/R7 (all BK=32, 24 steps, 68-76us invariant):
// halve the number of barrier-quantized steps. BK=64 makes LDS rows 128B =
// 16-way bank conflict on ds_read_b128 (G4), fixed per rule #21:
//   - global source col pre-swizzled: srccol8 = (l&7) ^ (row&7)  (8-short units)
//   - linear global_load_lds dest
//   - ds_read addr: slot8 = k8 ^ (row&7)  -> returns A[row][k8]  (verified)
// After swizzle each bank serves exactly 2 lanes per read (free, m136).
__global__ __launch_bounds__(256) void gemm_kernel(
    const short* __restrict__ A,    // patches bf16 [TOKENS][768]
    const short* __restrict__ Bw,   // Wbf bf16 [768][768]
    const float* __restrict__ bias,
    float* __restrict__ C) {
  __shared__ short As[2][128 * 64];   // 16KB each -> 64KB total, 2 blocks/CU
  __shared__ short Bs[2][128 * 64];

  const int tid  = threadIdx.x;
  const int w    = tid >> 6;
  const int l    = tid & 63;
  const int wrow = w >> 1;
  const int wcol = w & 1;
  const int lr   = l & 15;
  const int lg   = l >> 4;

  // bijective XCD swizzle: 1176 = 8*147 (R2 measured FETCH 118->34.6 MB)
  const int id  = blockIdx.x;
  const int nid = (id & 7) * 147 + (id >> 3);
  const int m0  = (nid / 6) * 128;
  const int n0  = (nid % 6) * 128;

  // bias pinned complete before staging (vmcnt ledger stays clean)
  float bs[4];
#pragma unroll
  for (int ni = 0; ni < 4; ++ni)
    bs[ni] = bias[n0 + wcol * 64 + ni * 16 + lr];
#pragma unroll
  for (int ni = 0; ni < 4; ++ni) asm volatile("" : "+v"(bs[ni]));

  f32x4 acc[4][4];
  const f32x4 z = {0.f, 0.f, 0.f, 0.f};
#pragma unroll
  for (int mi = 0; mi < 4; ++mi)
#pragma unroll
    for (int ni = 0; ni < 4; ++ni) acc[mi][ni] = z;

  // ---- staging: wave stages 32 rows x 64 cols per operand = 4 gload16 each.
  // gload16 covers 8 rows (lane l -> row l>>3, col-short ((l&7)^(l>>3))*8:
  // pre-swizzled source so the LINEAR LDS dest holds the swizzled image).
  const int srow = l >> 3;                       // row&7 within each 8-row chunk
  const int scol = ((l & 7) ^ srow) * 8;         // pre-swizzled source col
  const short* gA = A  + (size_t)(m0 + w * 32 + srow) * FDIM + scol;
  const short* gB = Bw + (size_t)(n0 + w * 32 + srow) * FDIM + scol;

#define STAGE(BUF, KT)                                                     \
  do {                                                                     \
    const int ko_ = (KT) * 64;                                             \
    _Pragma("unroll")                                                      \
    for (int c_ = 0; c_ < 4; ++c_) {                                       \
      gload16(gA + (size_t)c_ * 8 * FDIM + ko_,                            \
              &As[(BUF)][(w * 32 + c_ * 8) * 64]);                         \
      gload16(gB + (size_t)c_ * 8 * FDIM + ko_,                            \
              &Bs[(BUF)][(w * 32 + c_ * 8) * 64]);                         \
    }                                                                      \
  } while (0)

  // ---- swizzled fragment read: logical slot k8 = ks*4+lg lives at
  // (k8 ^ (row&7))*8; row&7 == lr&7 for all frag rows.
  const int rx  = lr & 7;
  const int rd0 = ((0 + lg) ^ rx) * 8;    // ks=0
  const int rd1 = ((4 + lg) ^ rx) * 8;    // ks=1

#define COMPUTE(BUF)                                                       \
  do {                                                                     \
    const short* Ab_ = As[(BUF)];                                          \
    const short* Bb_ = Bs[(BUF)];                                          \
    short8 a0_[4], b0_[4], a1_[4], b1_[4];                                 \
    _Pragma("unroll")                                                      \
    for (int mi = 0; mi < 4; ++mi) {                                       \
      const int r_ = (wrow * 64 + mi * 16 + lr) * 64;                      \
      a0_[mi] = *(const short8*)&Ab_[r_ + rd0];                            \
      a1_[mi] = *(const short8*)&Ab_[r_ + rd1];                            \
    }                                                                      \
    _Pragma("unroll")                                                      \
    for (int ni = 0; ni < 4; ++ni) {                                       \
      const int r_ = (wcol * 64 + ni * 16 + lr) * 64;                      \
      b0_[ni] = *(const short8*)&Bb_[r_ + rd0];                            \
      b1_[ni] = *(const short8*)&Bb_[r_ + rd1];                            \
    }                                                                      \
    __builtin_amdgcn_s_setprio(1);                                         \
    _Pragma("unroll")                                                      \
    for (int mi = 0; mi < 4; ++mi)                                         \
      _Pragma("unroll")                                                    \
      for (int ni = 0; ni < 4; ++ni) {                                     \
        acc[mi][ni] = __builtin_amdgcn_mfma_f32_16x16x32_bf16(             \
            a0_[mi], b0_[ni], acc[mi][ni], 0, 0, 0);                       \
        acc[mi][ni] = __builtin_amdgcn_mfma_f32_16x16x32_bf16(             \
            a1_[mi], b1_[ni], acc[mi][ni], 0, 0, 0);                       \
      }                                                                    \
    __builtin_amdgcn_s_setprio(0);                                         \
  } while (0)

  // prologue: tile 0 in flight
  STAGE(0, 0);

#pragma unroll 1
  for (int s = 0; s < 11; ++s) {
    STAGE((s + 1) & 1, s + 1);                       // 16 outstanding
    asm volatile("s_waitcnt vmcnt(8)" ::: "memory"); // tile s landed
    __builtin_amdgcn_s_barrier();
    COMPUTE(s & 1);
    asm volatile("s_waitcnt lgkmcnt(0)" ::: "memory");
    __builtin_amdgcn_sched_barrier(0);
    __builtin_amdgcn_s_barrier();
  }
  asm volatile("s_waitcnt vmcnt(0)" ::: "memory");
  __builtin_amdgcn_s_barrier();
  COMPUTE(1);                                        // tile 11

  // epilogue: C/D layout col = lane&15, row = (lane>>4)*4 + j
#pragma unroll
  for (int ni = 0; ni < 4; ++ni) {
    const int col = n0 + wcol * 64 + ni * 16 + lr;
#pragma unroll
    for (int mi = 0; mi < 4; ++mi) {
      const int row = m0 + wrow * 64 + mi * 16 + lg * 4;
      const f32x4 v = acc[mi][ni];
#pragma unroll
      for (int j = 0; j < 4; ++j)
        C[(size_t)(row + j) * DDIM + col] = v[j] + bs[ni];
    }
  }
#undef STAGE
#undef COMPUTE
}

// ---- fallback (ws too small): naive fused f32, correct but slow ----
__global__ __launch_bounds__(256) void naive_kernel(
    const float* __restrict__ x, const int* __restrict__ ys,
    const int* __restrict__ xs, const float* __restrict__ W,
    const float* __restrict__ bias, float* __restrict__ out) {
  __shared__ float prow[FDIM];
  const int tok = blockIdx.x;
  const int t   = threadIdx.x;
  const int b   = tok / NPATCH;
  const int y   = ys[tok];
  const int xc  = xs[tok];
  for (int i = t; i < FDIM; i += 256) {
    int c = i >> 8, rem = i & 255, py = rem >> 4, px = rem & 15;
    prow[i] = x[((size_t)(b * CH + c) * HW + y + py) * HW + xc + px];
  }
  __syncthreads();
  for (int dd = 0; dd < 3; ++dd) {
    const int d = t + dd * 256;
    float s = bias[d];
    const float4* wr = (const float4*)&W[(size_t)d * FDIM];
    const float4* pr = (const float4*)prow;
    for (int f4 = 0; f4 < FDIM / 4; ++f4) {
      float4 wv = wr[f4];
      float4 pv = pr[f4];
      s += wv.x * pv.x + wv.y * pv.y + wv.z * pv.z + wv.w * pv.w;
    }
    out[(size_t)tok * DDIM + d] = s;
  }
  if (t == 0) {
    float* pos = out + OUT_TOKENS;
    pos[(size_t)tok * 2]     = (float)y;
    pos[(size_t)tok * 2 + 1] = (float)xc;
  }
}

extern "C" void kernel_launch(void* const* d_in, const int* in_sizes, int n_in,
                              void* d_out, int out_size, void* d_ws, size_t ws_size,
                              hipStream_t stream) {
  const float* x    = (const float*)d_in[0];
  const int*   ys   = (const int*)d_in[1];
  const int*   xs   = (const int*)d_in[2];
  const float* W    = (const float*)d_in[3];
  const float* bias = (const float*)d_in[4];
  float* out = (float*)d_out;
  float* pos = out + OUT_TOKENS;

  const size_t w_bytes = (size_t)DDIM * FDIM * 2;
  const size_t p_bytes = TOKELEMS * 2;
  if (ws_size >= w_bytes + p_bytes) {
    short* Wbf     = (short*)d_ws;
    short* patches = (short*)d_ws + (size_t)DDIM * FDIM;
    prep_kernel<<<GATHER_BLOCKS + WCONV_BLOCKS, 256, 0, stream>>>(
        x, ys, xs, W, patches, Wbf, pos);
    gemm_kernel<<<(TOKENS / 128) * (DDIM / 128), 256, 0, stream>>>(
        patches, Wbf, bias, out);
  } else {
    naive_kernel<<<TOKENS, 256, 0, stream>>>(x, ys, xs, W, bias, out);
  }
}